// Round 3
// baseline (491.271 us; speedup 1.0000x reference)
//
#include <hip/hip_runtime.h>
#include <hip/hip_cooperative_groups.h>
#include <stdint.h>

namespace cg = cooperative_groups;

// BoltzmannGateSTE: out = x * (|x| >= T), T = k-th largest |x|, k = int(n/e).
// R3 structure (3 dispatches/iter):
//   memset (2.7 MB: state + fineH)
//   pass_partition  -- UNCHANGED from R0/R2 (proven BW-bound streaming loop):
//     stream x -> out with bracket [LO,HI) = [0.88,0.92): u>=HI keep+count chi;
//     u<LO zero; else candidate -> placeholder 0, ballot-compacted append to a
//     per-wave arena buffer + fire-and-forget atomicAdd into exact per-bit-
//     pattern table fineH[u-LO] (671K entries, ~1 hit/bin).
//   epilogue (cooperative, 1024x256, gated phases via grid.sync):
//     A: blocks<656 coarse-sum fineH; blocks 656..719 partial-reduce tallies.
//     B: block 0 verifies chi < k <= chi+tot, coarse+fine descending scans
//        (wave-shuffle scan, R2) -> exact threshold bits in state[S_T].
//     C: flag==0 -> wavecnt-guided fixup over candidate arena (reads only
//        valid prefixes, ~5.6 MB); flag!=0 -> full exact radix-select fallback
//        chain (zero, hist1, select1, hist2, select2, mask) inside the same
//        kernel -- never hot for this input (margins ~120 sigma), correctness
//        for arbitrary inputs.
// R1 lesson kept: the streaming pass stays a plain kernel (cooperative fusion
// of it serialized the loop: VGPR=12, 600 GB/s, 392 us).
// All flag/threshold cross-phase reads use device-scope atomic loads.

constexpr unsigned LO_BITS = 0x3F6147AEu;        // bits(0.88f)
constexpr unsigned HI_BITS = 0x3F6B851Fu;        // bits(0.92f)
constexpr unsigned NKEY    = HI_BITS - LO_BITS;  // 671089 bracket bit patterns
constexpr int      NCB     = (NKEY + 1023) / 1024;   // 656 coarse bins

constexpr int P_GRID = 4096;                 // partition geometry
constexpr int P_BLK  = 256;
constexpr int P_WPB  = P_BLK / 64;           // 4 waves/block
constexpr int NWAVES = P_GRID * P_WPB;       // 16384
constexpr int CAPW   = 128;                  // slots/wave (mean ~43, 13 sigma)

constexpr int EP_GRID = 1024;                // epilogue: 4 blocks/CU co-resident
constexpr int EP_BLK  = 256;
constexpr int EP_WPB  = EP_BLK / 64;
constexpr int TPART   = 64;                  // tally partial blocks

constexpr int NBIN1   = 4096;                // fallback: bits[30:19]
constexpr int NFINE   = 1 << 19;
constexpr int NCOARSE = 512;
constexpr int F_GRID  = 256;                 // tiny-ws fallback grids
constexpr int F_BLK   = 256;
#define SEL_T 1024

// state slots
#define S_PREF 0
#define S_K1   1
#define S_T    2
#define S_FLAG 3   // nonzero -> fallback chain active

__device__ __forceinline__ unsigned gread(unsigned* p) { return atomicAdd(p, 0u); }

// ---------------- fast path: partition (UNCHANGED, proven) ----------------
__global__ __launch_bounds__(P_BLK, 8)
void pass_partition(const uint4* __restrict__ x, long long n4,
                    uint4* __restrict__ out, uint2* __restrict__ cand,
                    unsigned* __restrict__ wavecnt, unsigned* __restrict__ blkchi,
                    unsigned* __restrict__ fineH, unsigned* __restrict__ state)
{
    typedef unsigned uv4 __attribute__((ext_vector_type(4)));
    const int lane  = threadIdx.x & 63;
    const int wid   = threadIdx.x >> 6;
    const int gwave = blockIdx.x * P_WPB + wid;
    uint2* my = cand + (size_t)gwave * CAPW;
    const unsigned long long lt = (1ull << lane) - 1ull;

    unsigned wcnt = 0;          // wave-uniform candidate count
    unsigned chi  = 0;          // per-thread >=HI tally
    const long long stride = (long long)gridDim.x * P_BLK;
#pragma unroll 2
    for (long long i = (long long)blockIdx.x * P_BLK + threadIdx.x; i < n4; i += stride) {
        uint4 v = x[i];
        uint4 r;
        unsigned idx0 = (unsigned)(i << 2);
#define DO_COMP(c, off)                                                        \
        { unsigned b = v.c, u = b & 0x7FFFFFFFu;                               \
          bool kp = (u >= HI_BITS);                                            \
          bool cd = (u >= LO_BITS) & !kp;                                      \
          chi += (unsigned)kp;                                                 \
          r.c = kp ? b : 0u;                                                   \
          unsigned long long m = __ballot(cd);                                 \
          if (cd) {                                                            \
              atomicAdd(&fineH[u - LO_BITS], 1u);  /* fire-and-forget */       \
              unsigned pos = wcnt + (unsigned)__popcll(m & lt);                \
              if (pos < (unsigned)CAPW) my[pos] = make_uint2(b, idx0 + off);   \
          }                                                                    \
          wcnt += (unsigned)__popcll(m); }
        DO_COMP(x, 0) DO_COMP(y, 1) DO_COMP(z, 2) DO_COMP(w, 3)
#undef DO_COMP
        __builtin_nontemporal_store(*(uv4*)&r, (uv4*)(out + i));
    }

    for (int m = 32; m; m >>= 1) chi += __shfl_xor(chi, m, 64);
    __shared__ unsigned s_chi[P_WPB];
    if (lane == 0) {
        s_chi[wid] = chi;
        wavecnt[gwave] = (wcnt < (unsigned)CAPW) ? wcnt : (unsigned)CAPW;
        if (wcnt > (unsigned)CAPW) atomicOr(&state[S_FLAG], 1u);
    }
    __syncthreads();
    if (threadIdx.x == 0) {
        unsigned a = 0;
        for (int w = 0; w < P_WPB; ++w) a += s_chi[w];
        blkchi[blockIdx.x] = a;
    }
}

// ---------------- descending select over a histogram (wave-shuffle scan) ----
template<int TB>
__device__ void select_desc_t(const unsigned* __restrict__ hist, int nbins,
                              unsigned k, unsigned* s_wsum, int* s_res)
{
    constexpr int TW = TB / 64;
    const int tid  = threadIdx.x;
    const int lane = tid & 63;
    const int wid  = tid >> 6;
    if (tid == 0) { s_res[0] = -1; s_res[1] = 0; }
    __syncthreads();
    unsigned running = 0;
    for (int top = nbins; top > 0; top -= TB) {
        int bin = top - 1 - tid;
        unsigned v = (bin >= 0) ? hist[bin] : 0u;
        unsigned p = v;
#pragma unroll
        for (int off = 1; off < 64; off <<= 1) {
            unsigned t = __shfl_up(p, off, 64);
            if (lane >= off) p += t;
        }
        if (lane == 63) s_wsum[wid] = p;
        __syncthreads();
        unsigned wpref = 0, total = 0;
#pragma unroll
        for (int w = 0; w < TW; ++w) {
            unsigned ws = s_wsum[w];
            wpref += (w < wid) ? ws : 0u;
            total += ws;
        }
        unsigned incl = wpref + p;      // inclusive prefix over whole block
        unsigned excl = incl - v;       // exclusive prefix
        if (running + total >= k) {     // block-uniform condition
            if (bin >= 0 && running + incl >= k && running + excl < k) {
                s_res[0] = bin;
                s_res[1] = (int)(k - running - excl);
            }
            __syncthreads();
            return;
        }
        running += total;
        __syncthreads();
    }
    __syncthreads();
}

// ---------------- cooperative epilogue ----------------
__global__ __launch_bounds__(EP_BLK, 4)
void epilogue(const uint4* __restrict__ x, long long n4, long long n,
              uint4* __restrict__ out,
              const uint2* __restrict__ cand,
              const unsigned* __restrict__ wavecnt,
              const unsigned* __restrict__ blkchi,
              const unsigned* __restrict__ fineH,
              unsigned* __restrict__ coarseH, uint2* __restrict__ tpart,
              unsigned* __restrict__ fineB, unsigned* __restrict__ coarseB,
              unsigned* __restrict__ histA,
              unsigned* __restrict__ state, unsigned k)
{
    cg::grid_group grid = cg::this_grid();
    __shared__ unsigned smem[NBIN1];     // fallback hists; unused in fast path
    __shared__ unsigned s_wsum[EP_BLK / 64];
    __shared__ unsigned s_small[8];
    __shared__ int s_res[2];

    const int tid  = threadIdx.x;
    const int lane = tid & 63;
    const int wid  = tid >> 6;
    const int bid  = blockIdx.x;

    // ---- phase A: coarse sums of fineH + tally partials ----
    if (bid < NCB) {
        unsigned base = (unsigned)bid << 10;
        unsigned s = 0;
        for (int t = tid; t < 1024; t += EP_BLK) {
            unsigned key = base + t;
            s += (key < NKEY) ? fineH[key] : 0u;
        }
        for (int m = 32; m; m >>= 1) s += __shfl_xor(s, m, 64);
        if (lane == 0) s_small[wid] = s;
        __syncthreads();
        if (tid == 0)
            coarseH[bid] = s_small[0] + s_small[1] + s_small[2] + s_small[3];
    } else if (bid < NCB + TPART) {
        int b = bid - NCB;
        unsigned chi = (tid < 64) ? blkchi[b * 64 + tid] : 0u;   // 4096 = 64*64
        unsigned tot = wavecnt[b * 256 + tid];                   // 16384 = 64*256
        for (int m = 32; m; m >>= 1) {
            chi += __shfl_xor(chi, m, 64);
            tot += __shfl_xor(tot, m, 64);
        }
        if (lane == 0) { s_small[wid] = chi; s_small[4 + wid] = tot; }
        __syncthreads();
        if (tid == 0)
            tpart[b] = make_uint2(s_small[0] + s_small[1] + s_small[2] + s_small[3],
                                  s_small[4] + s_small[5] + s_small[6] + s_small[7]);
    }

    grid.sync();

    // ---- phase B: block 0 verifies + selects exact threshold ----
    if (bid == 0) {
        unsigned fl0 = gread(&state[S_FLAG]);
        unsigned chi = 0, tot = 0;
        if (tid < TPART) { uint2 e = tpart[tid]; chi = e.x; tot = e.y; }
        for (int m = 32; m; m >>= 1) {
            chi += __shfl_xor(chi, m, 64);
            tot += __shfl_xor(tot, m, 64);
        }
        if (tid == 0) {
            if (fl0 == 0u && (chi >= k || chi + tot < k)) {
                atomicOr(&state[S_FLAG], 1u);      // bracket failed -> fallback
                fl0 = 1u;
            }
            s_small[0] = (fl0 == 0u) ? 1u : 0u;
            s_small[1] = k - chi;
        }
        __syncthreads();
        if (s_small[0]) {
            unsigned kp = s_small[1];
            select_desc_t<EP_BLK>(coarseH, NCB, kp, s_wsum, s_res);
            int cb     = s_res[0];
            unsigned r = (unsigned)s_res[1];
            __syncthreads();
            int nfine = (int)NKEY - cb * 1024;
            if (nfine > 1024) nfine = 1024;
            select_desc_t<EP_BLK>(fineH + (size_t)cb * 1024, nfine, r, s_wsum, s_res);
            if (tid == 0)
                atomicExch(&state[S_T], LO_BITS + (unsigned)(cb * 1024 + s_res[0]));
        }
    }

    grid.sync();

    // ---- phase C: fast fixup OR full exact fallback (grid-uniform branch) ----
    unsigned fl = gread(&state[S_FLAG]);
    if (fl == 0u) {
        unsigned T = gread(&state[S_T]);
        float* outF = (float*)out;
        int gw = bid * EP_WPB + wid;                       // 4096 grid waves
        for (int w = gw; w < NWAVES; w += EP_GRID * EP_WPB) {
            unsigned cnt = wavecnt[w];                     // valid prefix only
            const uint2* my = cand + (size_t)w * CAPW;
            for (unsigned j = (unsigned)lane; j < cnt; j += 64) {
                uint2 e = my[j];
                if ((e.x & 0x7FFFFFFFu) >= T && e.y < (unsigned long long)n)
                    outF[e.y] = __uint_as_float(e.x);
            }
        }
        return;   // all blocks return together (fl grid-uniform)
    }

    // ======== exact fallback, never hot; correctness for arbitrary inputs ====
    {   // zero fineB|coarseB|histA (contiguous span)
        long long zn = (long long)NFINE + NCOARSE + NBIN1;
        long long stride = (long long)EP_GRID * EP_BLK;
        for (long long i = (long long)bid * EP_BLK + tid; i < zn; i += stride)
            fineB[i] = 0u;
    }
    grid.sync();

    // hist1: bits[30:19]
    for (int i = tid; i < NBIN1; i += EP_BLK) smem[i] = 0u;
    __syncthreads();
    {
        long long stride = (long long)EP_GRID * EP_BLK;
        for (long long i = (long long)bid * EP_BLK + tid; i < n4; i += stride) {
            uint4 v = x[i];
            atomicAdd(&smem[(v.x & 0x7FFFFFFFu) >> 19], 1u);
            atomicAdd(&smem[(v.y & 0x7FFFFFFFu) >> 19], 1u);
            atomicAdd(&smem[(v.z & 0x7FFFFFFFu) >> 19], 1u);
            atomicAdd(&smem[(v.w & 0x7FFFFFFFu) >> 19], 1u);
        }
    }
    __syncthreads();
    for (int i = tid; i < NBIN1; i += EP_BLK)
        if (smem[i]) atomicAdd(&histA[i], smem[i]);
    grid.sync();

    if (bid == 0) {
        select_desc_t<EP_BLK>(histA, NBIN1, k, s_wsum, s_res);
        if (tid == 0) {
            atomicExch(&state[S_PREF], (s_res[0] < 0) ? 0u : (unsigned)s_res[0]);
            atomicExch(&state[S_K1],   (s_res[0] < 0) ? 1u : (unsigned)s_res[1]);
        }
    }
    grid.sync();

    // hist2: fine 19-bit histogram within prefix
    {
        unsigned pref = gread(&state[S_PREF]);
        for (int i = tid; i < NCOARSE; i += EP_BLK) smem[i] = 0u;
        __syncthreads();
        long long stride = (long long)EP_GRID * EP_BLK;
        for (long long i = (long long)bid * EP_BLK + tid; i < n4; i += stride) {
            uint4 v = x[i];
            unsigned u;
#define DO_C(c) u = v.c & 0x7FFFFFFFu;                                        \
            if ((u >> 19) == pref) {                                          \
                atomicAdd(&fineB[u & (NFINE - 1)], 1u);                       \
                atomicAdd(&smem[(u & (NFINE - 1)) >> 10], 1u); }
            DO_C(x) DO_C(y) DO_C(z) DO_C(w)
#undef DO_C
        }
        __syncthreads();
        for (int i = tid; i < NCOARSE; i += EP_BLK)
            if (smem[i]) atomicAdd(&coarseB[i], smem[i]);
    }
    grid.sync();

    if (bid == 0) {
        unsigned pref = gread(&state[S_PREF]);
        unsigned k1v  = gread(&state[S_K1]);
        select_desc_t<EP_BLK>(coarseB, NCOARSE, k1v, s_wsum, s_res);
        int c       = (s_res[0] < 0) ? 0 : s_res[0];
        unsigned k2 = (s_res[0] < 0) ? 1u : (unsigned)s_res[1];
        __syncthreads();
        select_desc_t<EP_BLK>(fineB + (size_t)c * 1024, 1024, k2, s_wsum, s_res);
        int f = (s_res[0] < 0) ? 0 : s_res[0];
        if (tid == 0)
            atomicExch(&state[S_T], (pref << 19) | ((unsigned)c << 10) | (unsigned)f);
    }
    grid.sync();

    {   // mask pass
        unsigned t = gread(&state[S_T]);
        long long stride = (long long)EP_GRID * EP_BLK;
        for (long long i = (long long)bid * EP_BLK + tid; i < n4; i += stride) {
            uint4 v = x[i];
            uint4 r;
            r.x = ((v.x & 0x7FFFFFFFu) >= t) ? v.x : 0u;
            r.y = ((v.y & 0x7FFFFFFFu) >= t) ? v.y : 0u;
            r.z = ((v.z & 0x7FFFFFFFu) >= t) ? v.z : 0u;
            r.w = ((v.w & 0x7FFFFFFFu) >= t) ? v.w : 0u;
            out[i] = r;
        }
    }
}

// ---------------- standalone exact chain (tiny-ws host path only) ----------
__global__ __launch_bounds__(F_BLK)
void f_hist1(const uint4* __restrict__ x, long long n4, unsigned* __restrict__ histA)
{
    __shared__ unsigned h[NBIN1];
    for (int i = threadIdx.x; i < NBIN1; i += F_BLK) h[i] = 0u;
    __syncthreads();
    long long stride = (long long)gridDim.x * F_BLK;
    for (long long i = (long long)blockIdx.x * F_BLK + threadIdx.x; i < n4; i += stride) {
        uint4 v = x[i];
        atomicAdd(&h[(v.x & 0x7FFFFFFFu) >> 19], 1u);
        atomicAdd(&h[(v.y & 0x7FFFFFFFu) >> 19], 1u);
        atomicAdd(&h[(v.z & 0x7FFFFFFFu) >> 19], 1u);
        atomicAdd(&h[(v.w & 0x7FFFFFFFu) >> 19], 1u);
    }
    __syncthreads();
    for (int i = threadIdx.x; i < NBIN1; i += F_BLK)
        if (h[i]) atomicAdd(&histA[i], h[i]);
}

__global__ __launch_bounds__(SEL_T)
void f_select1(const unsigned* __restrict__ histA, unsigned* __restrict__ state,
               unsigned k)
{
    __shared__ unsigned s_wsum[SEL_T / 64];
    __shared__ int s_res[2];
    select_desc_t<SEL_T>(histA, NBIN1, k, s_wsum, s_res);
    if (threadIdx.x == 0) {
        state[S_PREF] = (s_res[0] < 0) ? 0u : (unsigned)s_res[0];
        state[S_K1]   = (s_res[0] < 0) ? 1u : (unsigned)s_res[1];
    }
}

__global__ __launch_bounds__(F_BLK)
void f_hist2(const uint4* __restrict__ x, long long n4, const unsigned* __restrict__ state,
             unsigned* __restrict__ fineB, unsigned* __restrict__ coarseB)
{
    __shared__ unsigned hc[NCOARSE];
    for (int i = threadIdx.x; i < NCOARSE; i += F_BLK) hc[i] = 0u;
    __syncthreads();
    unsigned pref = state[S_PREF];
    long long stride = (long long)gridDim.x * F_BLK;
    for (long long i = (long long)blockIdx.x * F_BLK + threadIdx.x; i < n4; i += stride) {
        uint4 v = x[i];
        unsigned u;
#define DO_C(c) u = v.c & 0x7FFFFFFFu;                                        \
        if ((u >> 19) == pref) {                                              \
            atomicAdd(&fineB[u & (NFINE - 1)], 1u);                           \
            atomicAdd(&hc[(u & (NFINE - 1)) >> 10], 1u); }
        DO_C(x) DO_C(y) DO_C(z) DO_C(w)
#undef DO_C
    }
    __syncthreads();
    for (int i = threadIdx.x; i < NCOARSE; i += F_BLK)
        if (hc[i]) atomicAdd(&coarseB[i], hc[i]);
}

__global__ __launch_bounds__(SEL_T)
void f_select2(const unsigned* __restrict__ fineB, const unsigned* __restrict__ coarseB,
               unsigned* __restrict__ state)
{
    __shared__ unsigned s_wsum[SEL_T / 64];
    __shared__ int s_res[2];
    unsigned pref = state[S_PREF];
    unsigned k    = state[S_K1];
    select_desc_t<SEL_T>(coarseB, NCOARSE, k, s_wsum, s_res);
    int c       = (s_res[0] < 0) ? 0 : s_res[0];
    unsigned k1 = (s_res[0] < 0) ? 1u : (unsigned)s_res[1];
    __syncthreads();
    select_desc_t<SEL_T>(fineB + (size_t)c * 1024, 1024, k1, s_wsum, s_res);
    int f = (s_res[0] < 0) ? 0 : s_res[0];
    if (threadIdx.x == 0)
        state[S_T] = (pref << 19) | ((unsigned)c << 10) | (unsigned)f;
}

__global__ __launch_bounds__(256)
void f_mask(const uint4* __restrict__ x, uint4* __restrict__ out, long long n4,
            const unsigned* __restrict__ state)
{
    unsigned t = state[S_T];
    long long stride = (long long)gridDim.x * 256;
    for (long long i = (long long)blockIdx.x * 256 + threadIdx.x; i < n4; i += stride) {
        uint4 v = x[i];
        uint4 r;
        r.x = ((v.x & 0x7FFFFFFFu) >= t) ? v.x : 0u;
        r.y = ((v.y & 0x7FFFFFFFu) >= t) ? v.y : 0u;
        r.z = ((v.z & 0x7FFFFFFFu) >= t) ? v.z : 0u;
        r.w = ((v.w & 0x7FFFFFFFu) >= t) ? v.w : 0u;
        out[i] = r;
    }
}

// ---------------- host ----------------
extern "C" void kernel_launch(void* const* d_in, const int* in_sizes, int n_in,
                              void* d_out, int out_size, void* d_ws, size_t ws_size,
                              hipStream_t stream)
{
    long long n = (long long)in_sizes[0];
    if (n <= 0) return;
    long long n4 = n >> 2;   // n = 4*4096*2048, divisible by 4

    const double FRACTION = 1.0 / 2.718281828459045;   // matches Python 1.0/math.e
    long long k = (long long)((double)n * FRACTION);
    if (k < 1) k = 1;

    auto al = [](size_t v) { return (v + 63) & ~(size_t)63; };

    // fast layout: [state|fineH] zeroed; rest fully overwritten or lazily zeroed
    const size_t off_fineH   = 64;
    const size_t zero_end    = al(off_fineH + (size_t)NKEY * 4);     // ~2.7 MB
    const size_t off_coarseH = zero_end;
    const size_t off_tpart   = al(off_coarseH + (size_t)NCB * 4);
    const size_t off_wcnt    = al(off_tpart + (size_t)TPART * 8);
    const size_t off_bchi    = al(off_wcnt + (size_t)NWAVES * 4);
    const size_t off_cand    = al(off_bchi + (size_t)P_GRID * 4);
    const size_t off_fineB   = al(off_cand + (size_t)NWAVES * CAPW * 8);
    const size_t off_coarseB = off_fineB   + (size_t)NFINE * 4;      // contiguous
    const size_t off_histA   = off_coarseB + (size_t)NCOARSE * 4;    // contiguous
    const size_t need_fast   = off_histA   + (size_t)NBIN1 * 4;      // ~24 MB

    // compact fallback-only layout (tiny ws)
    const size_t fb_fineB   = 64;
    const size_t fb_coarseB = fb_fineB + (size_t)NFINE * 4;
    const size_t fb_histA   = fb_coarseB + (size_t)NCOARSE * 4;
    const size_t need_fb    = fb_histA + (size_t)NBIN1 * 4;          // ~2.1 MB

    const uint4* x = (const uint4*)d_in[0];

    if (ws_size >= need_fast) {
        uint8_t* base = (uint8_t*)d_ws;
        unsigned* state   = (unsigned*)base;
        unsigned* fineH   = (unsigned*)(base + off_fineH);
        unsigned* coarseH = (unsigned*)(base + off_coarseH);
        uint2*    tpart   = (uint2*)   (base + off_tpart);
        unsigned* wavecnt = (unsigned*)(base + off_wcnt);
        unsigned* blkchi  = (unsigned*)(base + off_bchi);
        uint2*    cand    = (uint2*)   (base + off_cand);
        unsigned* fineB   = (unsigned*)(base + off_fineB);
        unsigned* coarseB = (unsigned*)(base + off_coarseB);
        unsigned* histA   = (unsigned*)(base + off_histA);

        hipMemsetAsync(base, 0, zero_end, stream);     // state + fineH only
        pass_partition<<<P_GRID, P_BLK, 0, stream>>>(x, n4, (uint4*)d_out, cand,
                                                     wavecnt, blkchi, fineH, state);
        const uint4* xp = x;  long long n4v = n4, nv = n;
        uint4* outp = (uint4*)d_out;
        const uint2* candp = cand;
        const unsigned* wcp = wavecnt; const unsigned* bcp = blkchi;
        const unsigned* fHp = fineH;
        unsigned* cHp = coarseH; uint2* tpp = tpart;
        unsigned* fBp = fineB; unsigned* cBp = coarseB; unsigned* hAp = histA;
        unsigned* stp = state; unsigned kv = (unsigned)k;
        void* args[] = { (void*)&xp, (void*)&n4v, (void*)&nv, (void*)&outp,
                         (void*)&candp, (void*)&wcp, (void*)&bcp, (void*)&fHp,
                         (void*)&cHp, (void*)&tpp, (void*)&fBp, (void*)&cBp,
                         (void*)&hAp, (void*)&stp, (void*)&kv };
        hipLaunchCooperativeKernel((void*)epilogue, dim3(EP_GRID), dim3(EP_BLK),
                                   args, 0, stream);
    } else {
        // tiny workspace: always-on exact radix chain (stage in d_out if needed)
        uint8_t* base;
        unsigned* state = (unsigned*)d_ws;
        if (ws_size >= need_fb) { base = (uint8_t*)d_ws; }
        else                    { base = (uint8_t*)d_out; }   // stage hists in d_out
        unsigned* fineB   = (unsigned*)(base + fb_fineB);
        unsigned* coarseB = (unsigned*)(base + fb_coarseB);
        unsigned* histA   = (unsigned*)(base + fb_histA);

        hipMemsetAsync(state, 0, 64, stream);
        hipMemsetAsync(base + fb_fineB, 0,
                       ((size_t)NFINE + NCOARSE + NBIN1) * 4, stream);
        f_hist1  <<<F_GRID, F_BLK, 0, stream>>>(x, n4, histA);
        f_select1<<<1, SEL_T, 0, stream>>>(histA, state, (unsigned)k);
        f_hist2  <<<F_GRID, F_BLK, 0, stream>>>(x, n4, state, fineB, coarseB);
        f_select2<<<1, SEL_T, 0, stream>>>(fineB, coarseB, state);
        f_mask   <<<1024, 256, 0, stream>>>(x, (uint4*)d_out, n4, state);
    }
}

// Round 4
// 299.607 us; speedup vs baseline: 1.6397x; 1.6397x over previous
//
#include <hip/hip_runtime.h>
#include <stdint.h>

// BoltzmannGateSTE: out = x * (|x| >= T), T = k-th largest |x|, k = int(n/e).
// R4 structure (5 dispatches + 1 memset; NO cooperative sync):
//   memset (~4.8 MB: state + fineH + fallback hists)
//   pass_partition -- BYTE-IDENTICAL to R0/R2 (proven BW-bound streaming loop):
//     stream x -> out with bracket [LO,HI)=[0.88,0.92): u>=HI keep+count chi;
//     u<LO zero; else candidate -> placeholder 0, ballot-compacted append to a
//     per-wave arena buffer + fire-and-forget atomicAdd into exact per-bit-
//     pattern table fineH[u-LO] (671K entries, ~1 hit/bin).
//   kcs: 656 blocks coarse-sum fineH + 64 blocks pack (chi,tot) partials;
//     LAST-BLOCK TICKET (threadfence + atomicAdd) -> winner verifies
//     chi < k <= chi+tot and runs coarse+fine descending wave-shuffle scans
//     -> exact threshold bits in state[S_T].
//   post1: flag==0 -> wavecnt-guided fixup (valid arena prefixes only, ~5.6MB);
//          flag!=0 -> fallback hist1 (4096 bins) + last-block select1.
//   post2: gated fallback hist2 (2^19 fine bins) + last-block select2.
//   post3: gated fallback mask pass.
// MEASURED LESSONS ENCODED HERE:
//   R1/R3: cg::grid.sync() costs ~115 us EACH on MI355X under graph capture
//     (2 syncs = 228 us epilogue; 3 syncs explained R1's 392 us). NEVER use
//     cooperative kernels here; plain dispatch boundaries cost ~2-3 us.
//     Last-block ticket (fence+atomic) replaces cross-block sync for free.
//   R2: select scan barriers were only ~0.6 us; partition is ~60 us (~70% of
//     its 43 us HBM floor); harness re-poison fills ~180 us are untouchable.
// Exact gated fallback covers arbitrary inputs if the bracket or a wave buffer
// fails verification (deterministically never for this input; ~120 sigma).

constexpr unsigned LO_BITS = 0x3F6147AEu;        // bits(0.88f)
constexpr unsigned HI_BITS = 0x3F6B851Fu;        // bits(0.92f)
constexpr unsigned NKEY    = HI_BITS - LO_BITS;  // 671089 bracket bit patterns
constexpr int      NCB     = (NKEY + 1023) / 1024;   // 656 coarse bins

constexpr int P_GRID = 4096;                 // partition geometry
constexpr int P_BLK  = 256;
constexpr int P_WPB  = P_BLK / 64;           // 4 waves/block
constexpr int NWAVES = P_GRID * P_WPB;       // 16384
constexpr int CAPW   = 128;                  // slots/wave (mean ~43, 13 sigma)

constexpr int TPART  = 64;                   // tally partial blocks in kcs
constexpr int KCS_GRID = NCB + TPART;        // 720

constexpr int NBIN1   = 4096;                // fallback: bits[30:19]
constexpr int NFINE   = 1 << 19;
constexpr int NCOARSE = 512;

// state slots
#define S_PREF 0
#define S_K1   1
#define S_T    2
#define S_FLAG 3   // nonzero -> fallback chain active
#define S_TICK 4   // kcs last-block ticket
#define S_TICK2 5  // post1 fallback ticket
#define S_TICK3 6  // post2 fallback ticket

// ---------------- fast path: partition (UNCHANGED, proven) ----------------
__global__ __launch_bounds__(P_BLK, 8)
void pass_partition(const uint4* __restrict__ x, long long n4,
                    uint4* __restrict__ out, uint2* __restrict__ cand,
                    unsigned* __restrict__ wavecnt, unsigned* __restrict__ blkchi,
                    unsigned* __restrict__ fineH, unsigned* __restrict__ state)
{
    typedef unsigned uv4 __attribute__((ext_vector_type(4)));
    const int lane  = threadIdx.x & 63;
    const int wid   = threadIdx.x >> 6;
    const int gwave = blockIdx.x * P_WPB + wid;
    uint2* my = cand + (size_t)gwave * CAPW;
    const unsigned long long lt = (1ull << lane) - 1ull;

    unsigned wcnt = 0;          // wave-uniform candidate count
    unsigned chi  = 0;          // per-thread >=HI tally
    const long long stride = (long long)gridDim.x * P_BLK;
#pragma unroll 2
    for (long long i = (long long)blockIdx.x * P_BLK + threadIdx.x; i < n4; i += stride) {
        uint4 v = x[i];
        uint4 r;
        unsigned idx0 = (unsigned)(i << 2);
#define DO_COMP(c, off)                                                        \
        { unsigned b = v.c, u = b & 0x7FFFFFFFu;                               \
          bool kp = (u >= HI_BITS);                                            \
          bool cd = (u >= LO_BITS) & !kp;                                      \
          chi += (unsigned)kp;                                                 \
          r.c = kp ? b : 0u;                                                   \
          unsigned long long m = __ballot(cd);                                 \
          if (cd) {                                                            \
              atomicAdd(&fineH[u - LO_BITS], 1u);  /* fire-and-forget */       \
              unsigned pos = wcnt + (unsigned)__popcll(m & lt);                \
              if (pos < (unsigned)CAPW) my[pos] = make_uint2(b, idx0 + off);   \
          }                                                                    \
          wcnt += (unsigned)__popcll(m); }
        DO_COMP(x, 0) DO_COMP(y, 1) DO_COMP(z, 2) DO_COMP(w, 3)
#undef DO_COMP
        __builtin_nontemporal_store(*(uv4*)&r, (uv4*)(out + i));
    }

    for (int m = 32; m; m >>= 1) chi += __shfl_xor(chi, m, 64);
    __shared__ unsigned s_chi[P_WPB];
    if (lane == 0) {
        s_chi[wid] = chi;
        wavecnt[gwave] = (wcnt < (unsigned)CAPW) ? wcnt : (unsigned)CAPW;
        if (wcnt > (unsigned)CAPW) atomicOr(&state[S_FLAG], 1u);
    }
    __syncthreads();
    if (threadIdx.x == 0) {
        unsigned a = 0;
        for (int w = 0; w < P_WPB; ++w) a += s_chi[w];
        blkchi[blockIdx.x] = a;
    }
}

// ---- descending single-chunk select over nbins<=1024 (1024-thread block) ----
__device__ __forceinline__ void select1k(const unsigned* __restrict__ hist, int nbins,
                                         unsigned k, unsigned* s_wsum, int* s_res)
{
    const int tid = threadIdx.x, lane = tid & 63, wid = tid >> 6;
    __syncthreads();                       // protect caller's s_res reads
    if (tid == 0) { s_res[0] = 0; s_res[1] = 1; }   // safe default
    int bin = nbins - 1 - tid;
    unsigned v = (bin >= 0) ? hist[bin] : 0u;
    unsigned p = v;
#pragma unroll
    for (int off = 1; off < 64; off <<= 1) {
        unsigned t = __shfl_up(p, off, 64);
        if (lane >= off) p += t;
    }
    if (lane == 63) s_wsum[wid] = p;
    __syncthreads();
    unsigned wpref = 0;
#pragma unroll
    for (int w = 0; w < 16; ++w) {
        unsigned ws = s_wsum[w];
        wpref += (w < wid) ? ws : 0u;
    }
    unsigned incl = wpref + p, excl = incl - v;
    if (bin >= 0 && incl >= k && excl < k) {   // exactly one thread (k<=total)
        s_res[0] = bin;
        s_res[1] = (int)(k - excl);
    }
    __syncthreads();
}

// ---- descending chunked select (TB-thread block, any nbins) ----
template<int TB>
__device__ void select_desc_t(const unsigned* __restrict__ hist, int nbins,
                              unsigned k, unsigned* s_wsum, int* s_res)
{
    constexpr int TW = TB / 64;
    const int tid  = threadIdx.x;
    const int lane = tid & 63;
    const int wid  = tid >> 6;
    __syncthreads();
    if (tid == 0) { s_res[0] = -1; s_res[1] = 0; }
    __syncthreads();
    unsigned running = 0;
    for (int top = nbins; top > 0; top -= TB) {
        int bin = top - 1 - tid;
        unsigned v = (bin >= 0) ? hist[bin] : 0u;
        unsigned p = v;
#pragma unroll
        for (int off = 1; off < 64; off <<= 1) {
            unsigned t = __shfl_up(p, off, 64);
            if (lane >= off) p += t;
        }
        if (lane == 63) s_wsum[wid] = p;
        __syncthreads();
        unsigned wpref = 0, total = 0;
#pragma unroll
        for (int w = 0; w < TW; ++w) {
            unsigned ws = s_wsum[w];
            wpref += (w < wid) ? ws : 0u;
            total += ws;
        }
        unsigned incl = wpref + p;
        unsigned excl = incl - v;
        if (running + total >= k) {     // block-uniform
            if (bin >= 0 && running + incl >= k && running + excl < k) {
                s_res[0] = bin;
                s_res[1] = (int)(k - running - excl);
            }
            __syncthreads();
            return;
        }
        running += total;
        __syncthreads();
    }
    __syncthreads();
}

// ---- kcs: coarse sums + tally partials + last-block verify/select ----
__global__ __launch_bounds__(1024)
void kcs(const unsigned* __restrict__ fineH,
         const unsigned* __restrict__ blkchi, const unsigned* __restrict__ wavecnt,
         unsigned* __restrict__ coarseH, unsigned long long* __restrict__ tpart,
         unsigned* __restrict__ state, unsigned k)
{
    __shared__ unsigned s_t[16];
    __shared__ unsigned s_wsum[16];
    __shared__ int s_res[2];
    __shared__ unsigned s_ct[2];
    __shared__ unsigned s_done;

    const int tid = threadIdx.x, lane = tid & 63, wid = tid >> 6;
    const int bid = blockIdx.x;

    if (bid < NCB) {
        unsigned key = ((unsigned)bid << 10) + (unsigned)tid;
        unsigned s = (key < NKEY) ? fineH[key] : 0u;
        for (int m = 32; m; m >>= 1) s += __shfl_xor(s, m, 64);
        if (lane == 0) s_t[wid] = s;
        __syncthreads();
        if (tid == 0) {
            unsigned a = 0;
#pragma unroll
            for (int w = 0; w < 16; ++w) a += s_t[w];
            coarseH[bid] = a;
        }
    } else {
        int b = bid - NCB;                                   // 0..63
        unsigned chi = (tid < 64)  ? blkchi[(b << 6) + tid]  : 0u;  // 4096=64*64
        unsigned tot = (tid < 256) ? wavecnt[(b << 8) + tid] : 0u;  // 16384=64*256
        for (int m = 32; m; m >>= 1) {
            chi += __shfl_xor(chi, m, 64);
            tot += __shfl_xor(tot, m, 64);
        }
        if (lane == 0) s_t[wid] = tot;
        __syncthreads();
        if (tid == 0) {                                      // tid0 = lane0 wave0
            unsigned tt = 0;
#pragma unroll
            for (int w = 0; w < 16; ++w) tt += s_t[w];
            tpart[b] = ((unsigned long long)chi << 32) | (unsigned long long)tt;
        }
    }
    __syncthreads();

    // last-block ticket: release writes, grab ticket; winner proceeds
    if (tid == 0) { __threadfence(); s_done = atomicAdd(&state[S_TICK], 1u); }
    __syncthreads();
    if (s_done != (unsigned)(KCS_GRID - 1)) return;
    __threadfence();                                          // acquire

    unsigned long long chiS = 0, totS = 0;
    if (wid == 0) {
        unsigned long long e = tpart[lane];                   // TPART == 64
        chiS = e >> 32; totS = e & 0xFFFFFFFFull;
        for (int m = 32; m; m >>= 1) {
            chiS += __shfl_xor(chiS, m, 64);
            totS += __shfl_xor(totS, m, 64);
        }
    }
    if (tid == 0) {
        unsigned fl = state[S_FLAG];
        if (fl == 0u && (chiS >= (unsigned long long)k ||
                         chiS + totS < (unsigned long long)k)) {
            atomicOr(&state[S_FLAG], 1u);    // bracket failed -> fallback
            fl = 1u;
        }
        s_ct[0] = (fl == 0u) ? 1u : 0u;
        s_ct[1] = (unsigned)((unsigned long long)k - chiS);
    }
    __syncthreads();
    if (!s_ct[0]) return;
    unsigned kp = s_ct[1];

    select1k(coarseH, NCB, kp, s_wsum, s_res);
    int cb = s_res[0];
    unsigned r = (unsigned)s_res[1];
    int nfine = (int)NKEY - (cb << 10);
    if (nfine > 1024) nfine = 1024;
    select1k(fineH + ((size_t)cb << 10), nfine, r, s_wsum, s_res);
    if (tid == 0)
        state[S_T] = LO_BITS + (unsigned)((cb << 10) + s_res[0]);
}

// ---- post1: fast fixup OR fallback hist1+select1 ----
__global__ __launch_bounds__(256, 8)
void post1(const uint4* __restrict__ x, long long n4, long long n,
           float* __restrict__ outF,
           const uint2* __restrict__ cand, const unsigned* __restrict__ wavecnt,
           unsigned* __restrict__ histA, unsigned* __restrict__ state, unsigned k)
{
    const int tid = threadIdx.x, lane = tid & 63, wid = tid >> 6;

    if (state[S_FLAG] == 0u) {
        // wavecnt-guided fixup: read only valid prefixes (~5.6 MB not 16.8 MB)
        unsigned T = state[S_T];
        int gw = blockIdx.x * 4 + wid;
        int gstride = (int)gridDim.x * 4;
        for (int w = gw; w < NWAVES; w += gstride) {
            unsigned cnt = wavecnt[w];
            const uint2* my = cand + (size_t)w * CAPW;
            for (unsigned j = (unsigned)lane; j < cnt; j += 64) {
                uint2 e = my[j];
                if ((e.x & 0x7FFFFFFFu) >= T && (long long)e.y < n)
                    outF[e.y] = __uint_as_float(e.x);
            }
        }
        return;
    }

    // ---- fallback: 4096-bin histogram of bits[30:19] ----
    __shared__ unsigned h[NBIN1];
    for (int i = tid; i < NBIN1; i += 256) h[i] = 0u;
    __syncthreads();
    long long stride = (long long)gridDim.x * 256;
    for (long long i = (long long)blockIdx.x * 256 + tid; i < n4; i += stride) {
        uint4 v = x[i];
        atomicAdd(&h[(v.x & 0x7FFFFFFFu) >> 19], 1u);
        atomicAdd(&h[(v.y & 0x7FFFFFFFu) >> 19], 1u);
        atomicAdd(&h[(v.z & 0x7FFFFFFFu) >> 19], 1u);
        atomicAdd(&h[(v.w & 0x7FFFFFFFu) >> 19], 1u);
    }
    __syncthreads();
    for (int i = tid; i < NBIN1; i += 256)
        if (h[i]) atomicAdd(&histA[i], h[i]);
    __syncthreads();

    __shared__ unsigned s_done;
    if (tid == 0) { __threadfence(); s_done = atomicAdd(&state[S_TICK2], 1u); }
    __syncthreads();
    if (s_done != gridDim.x - 1) return;
    __threadfence();

    __shared__ unsigned s_wsum[4];
    __shared__ int s_res[2];
    select_desc_t<256>(histA, NBIN1, k, s_wsum, s_res);
    if (tid == 0) {
        state[S_PREF] = (s_res[0] < 0) ? 0u : (unsigned)s_res[0];
        state[S_K1]   = (s_res[0] < 0) ? 1u : (unsigned)s_res[1];
    }
}

// ---- post2: gated fallback hist2+select2 ----
__global__ __launch_bounds__(256, 8)
void post2(const uint4* __restrict__ x, long long n4,
           unsigned* __restrict__ fineB, unsigned* __restrict__ coarseB,
           unsigned* __restrict__ state)
{
    if (state[S_FLAG] == 0u) return;
    const int tid = threadIdx.x;
    unsigned pref = state[S_PREF];

    __shared__ unsigned hc[NCOARSE];
    for (int i = tid; i < NCOARSE; i += 256) hc[i] = 0u;
    __syncthreads();
    long long stride = (long long)gridDim.x * 256;
    for (long long i = (long long)blockIdx.x * 256 + tid; i < n4; i += stride) {
        uint4 v = x[i];
        unsigned u;
#define DO_C(c) u = v.c & 0x7FFFFFFFu;                                        \
        if ((u >> 19) == pref) {                                              \
            atomicAdd(&fineB[u & (NFINE - 1)], 1u);                           \
            atomicAdd(&hc[(u & (NFINE - 1)) >> 10], 1u); }
        DO_C(x) DO_C(y) DO_C(z) DO_C(w)
#undef DO_C
    }
    __syncthreads();
    for (int i = tid; i < NCOARSE; i += 256)
        if (hc[i]) atomicAdd(&coarseB[i], hc[i]);
    __syncthreads();

    __shared__ unsigned s_done;
    if (tid == 0) { __threadfence(); s_done = atomicAdd(&state[S_TICK3], 1u); }
    __syncthreads();
    if (s_done != gridDim.x - 1) return;
    __threadfence();

    __shared__ unsigned s_wsum[4];
    __shared__ int s_res[2];
    unsigned k1 = state[S_K1];
    select_desc_t<256>(coarseB, NCOARSE, k1, s_wsum, s_res);
    int c       = (s_res[0] < 0) ? 0 : s_res[0];
    unsigned k2 = (s_res[0] < 0) ? 1u : (unsigned)s_res[1];
    __syncthreads();
    select_desc_t<256>(fineB + (size_t)c * 1024, 1024, k2, s_wsum, s_res);
    int f = (s_res[0] < 0) ? 0 : s_res[0];
    if (tid == 0)
        state[S_T] = (pref << 19) | ((unsigned)c << 10) | (unsigned)f;
}

// ---- post3: gated fallback mask pass ----
__global__ __launch_bounds__(256)
void post3(const uint4* __restrict__ x, uint4* __restrict__ out, long long n4,
           const unsigned* __restrict__ state)
{
    if (state[S_FLAG] == 0u) return;
    unsigned t = state[S_T];
    long long stride = (long long)gridDim.x * 256;
    for (long long i = (long long)blockIdx.x * 256 + threadIdx.x; i < n4; i += stride) {
        uint4 v = x[i];
        uint4 r;
        r.x = ((v.x & 0x7FFFFFFFu) >= t) ? v.x : 0u;
        r.y = ((v.y & 0x7FFFFFFFu) >= t) ? v.y : 0u;
        r.z = ((v.z & 0x7FFFFFFFu) >= t) ? v.z : 0u;
        r.w = ((v.w & 0x7FFFFFFFu) >= t) ? v.w : 0u;
        out[i] = r;
    }
}

__global__ void seed_flag(unsigned* state)
{
    if (threadIdx.x == 0) state[S_FLAG] = 1u;
}

// ---------------- host ----------------
extern "C" void kernel_launch(void* const* d_in, const int* in_sizes, int n_in,
                              void* d_out, int out_size, void* d_ws, size_t ws_size,
                              hipStream_t stream)
{
    long long n = (long long)in_sizes[0];
    if (n <= 0) return;
    long long n4 = n >> 2;   // n = 4*4096*2048, divisible by 4

    const double FRACTION = 1.0 / 2.718281828459045;   // matches Python 1.0/math.e
    long long k = (long long)((double)n * FRACTION);
    if (k < 1) k = 1;

    auto al = [](size_t v) { return (v + 63) & ~(size_t)63; };

    // zeroed region: state | fineH | fineB | coarseB | histA  (~4.8 MB)
    const size_t off_fineH   = 64;
    const size_t off_fineB   = al(off_fineH + (size_t)NKEY * 4);
    const size_t off_coarseB = off_fineB   + (size_t)NFINE * 4;    // contiguous
    const size_t off_histA   = off_coarseB + (size_t)NCOARSE * 4;  // contiguous
    const size_t zero_end    = off_histA   + (size_t)NBIN1 * 4;
    // non-zeroed region (fully overwritten each iteration)
    const size_t off_coarseH = al(zero_end);
    const size_t off_tpart   = al(off_coarseH + (size_t)NCB * 4);
    const size_t off_wcnt    = al(off_tpart + (size_t)TPART * 8);
    const size_t off_bchi    = al(off_wcnt + (size_t)NWAVES * 4);
    const size_t off_cand    = al(off_bchi + (size_t)P_GRID * 4);
    const size_t need_fast   = off_cand + (size_t)NWAVES * CAPW * 8;   // ~26 MB
    const size_t need_fb     = zero_end;

    const uint4* x = (const uint4*)d_in[0];

    if (ws_size >= need_fast) {
        uint8_t* base = (uint8_t*)d_ws;
        unsigned* state   = (unsigned*)base;
        unsigned* fineH   = (unsigned*)(base + off_fineH);
        unsigned* fineB   = (unsigned*)(base + off_fineB);
        unsigned* coarseB = (unsigned*)(base + off_coarseB);
        unsigned* histA   = (unsigned*)(base + off_histA);
        unsigned* coarseH = (unsigned*)(base + off_coarseH);
        unsigned long long* tpart = (unsigned long long*)(base + off_tpart);
        unsigned* wavecnt = (unsigned*)(base + off_wcnt);
        unsigned* blkchi  = (unsigned*)(base + off_bchi);
        uint2*    cand    = (uint2*)   (base + off_cand);

        hipMemsetAsync(base, 0, zero_end, stream);
        pass_partition<<<P_GRID, P_BLK, 0, stream>>>(x, n4, (uint4*)d_out, cand,
                                                     wavecnt, blkchi, fineH, state);
        kcs  <<<KCS_GRID, 1024, 0, stream>>>(fineH, blkchi, wavecnt, coarseH,
                                             tpart, state, (unsigned)k);
        post1<<<1024, 256, 0, stream>>>(x, n4, n, (float*)d_out, cand, wavecnt,
                                        histA, state, (unsigned)k);
        post2<<<256, 256, 0, stream>>>(x, n4, fineB, coarseB, state);
        post3<<<1024, 256, 0, stream>>>(x, (uint4*)d_out, n4, state);
    } else {
        // tiny workspace: run the exact fallback chain unconditionally
        uint8_t* base;
        unsigned* state = (unsigned*)d_ws;       // 64 B state always in d_ws
        bool in_ws = (ws_size >= need_fb);
        base = in_ws ? (uint8_t*)d_ws : (uint8_t*)d_out;  // stage hists in d_out
        unsigned* fineB   = (unsigned*)(base + off_fineB);
        unsigned* coarseB = (unsigned*)(base + off_coarseB);
        unsigned* histA   = (unsigned*)(base + off_histA);

        if (in_ws) {
            hipMemsetAsync(base, 0, zero_end, stream);
        } else {
            hipMemsetAsync(state, 0, 64, stream);
            hipMemsetAsync(base + off_fineB, 0,
                           ((size_t)NFINE + NCOARSE + NBIN1) * 4, stream);
        }
        seed_flag<<<1, 64, 0, stream>>>(state);
        post1<<<1024, 256, 0, stream>>>(x, n4, n, (float*)d_out,
                                        (const uint2*)base, (const unsigned*)base,
                                        histA, state, (unsigned)k);
        post2<<<256, 256, 0, stream>>>(x, n4, fineB, coarseB, state);
        post3<<<1024, 256, 0, stream>>>(x, (uint4*)d_out, n4, state);
    }
}